// Round 9
// baseline (487.705 us; speedup 1.0000x reference)
//
#include <hip/hip_runtime.h>
#include <math.h>

#define Nn 102400
#define Gg 256
#define Pp 400
#define Ee 3276800
#define Ff 128
#define Kk 30
#define Cc 97

#define GSTRIDE 16384     // col slots per graph (avg fill 12800, sd ~113)
#define CHUNK 8192        // edges per binsort block
#define NBS 400           // binsort blocks

// ---------------- K1: binsort (blocks 0..399)  ||  gemm 128->32 (blocks 400..3599) ----
struct BSmem {
    unsigned reord[CHUNK];        // 32 KB
    unsigned char sg[CHUNK];      // 8 KB
    int cntl[Gg];
    int ginc[Gg];
    int gex[Gg];
    int gbase[Gg];
    int cur[Gg];
};
struct GMmem {
    float Wl[128 * 32];           // 16 KB
    float hrow[32][128];          // 16 KB
};
union KUmem { BSmem bs; GMmem gm; };

__global__ void __launch_bounds__(1024) k_bs_gemm(const int* __restrict__ ei,
                                                  int* __restrict__ gcnt,
                                                  unsigned* __restrict__ bucket,
                                                  const float* __restrict__ x,
                                                  const float* __restrict__ W1,
                                                  float* __restrict__ hw) {
    __shared__ __align__(16) KUmem u;
    int t = threadIdx.x;
    if (blockIdx.x < NBS) {
        // ---- binsort role ----
        int base = blockIdx.x * CHUNK;
        for (int i = t; i < Gg; i += 1024) u.bs.cntl[i] = 0;
        __syncthreads();
        unsigned val[8];
        int vg[8];
        bool ok[8];
#pragma unroll
        for (int j = 0; j < 8; j++) {
            int e = base + j * 1024 + t;
            int s = ei[e], d = ei[Ee + e];
            ok[j] = (s != d);
            int gph = d / Pp;
            vg[j] = gph;
            val[j] = (unsigned)s | ((unsigned)(d - gph * Pp) << 17);
            if (ok[j]) atomicAdd(&u.bs.cntl[gph], 1);
        }
        __syncthreads();
        if (t < Gg) u.bs.ginc[t] = u.bs.cntl[t];
        __syncthreads();
        for (int off = 1; off < Gg; off <<= 1) {
            int v = 0;
            if (t < Gg && t >= off) v = u.bs.ginc[t - off];
            __syncthreads();
            if (t < Gg) u.bs.ginc[t] += v;
            __syncthreads();
        }
        if (t < Gg) {
            int ex = u.bs.ginc[t] - u.bs.cntl[t];
            u.bs.gex[t] = ex;
            u.bs.cur[t] = ex;
            u.bs.gbase[t] = atomicAdd(&gcnt[t], u.bs.cntl[t]);
        }
        __syncthreads();
#pragma unroll
        for (int j = 0; j < 8; j++)
            if (ok[j]) {
                int pos = atomicAdd(&u.bs.cur[vg[j]], 1);
                u.bs.reord[pos] = val[j];
                u.bs.sg[pos] = (unsigned char)vg[j];
            }
        __syncthreads();
        int tot = u.bs.ginc[Gg - 1];
        for (int i = t; i < tot; i += 1024) {
            int g = u.bs.sg[i];
            bucket[g * GSTRIDE + u.bs.gbase[g] + (i - u.bs.gex[g])] = u.bs.reord[i];
        }
    } else {
        // ---- gemm role: 32 rows/block ----
        ((float4*)u.gm.Wl)[t] = ((const float4*)W1)[t];
        int grp = t >> 5, c = t & 31;
        int n = (blockIdx.x - NBS) * 32 + grp;
        ((float4*)u.gm.hrow[grp])[c] = ((const float4*)(x + (size_t)n * 128))[c];
        __syncthreads();
        float acc = 0.f;
#pragma unroll 8
        for (int k = 0; k < 128; k++) acc += u.gm.hrow[grp][k] * u.gm.Wl[k * 32 + c];
        hw[(size_t)n * 32 + c] = acc;
    }
}

// ---------------- CSR build: per-graph counting sort + dis + scale hw by dis ---------
__global__ void __launch_bounds__(1024) k_build(const int* __restrict__ gcnt,
                                                unsigned* __restrict__ bucket, /* also col out */
                                                int* __restrict__ row_start,
                                                int* __restrict__ cnt_g,
                                                float* __restrict__ dis,
                                                float4* __restrict__ hwv) {
    __shared__ unsigned pairs[GSTRIDE];   // 64 KB stash
    __shared__ int cntl[Pp];
    __shared__ int curl[Pp];
    __shared__ int sc[512];
    int g = blockIdx.x, t = threadIdx.x;
    int tot = gcnt[g];
    if (tot > GSTRIDE) tot = GSTRIDE;
    const unsigned* srcp = bucket + (size_t)g * GSTRIDE;
    for (int i = t; i < tot; i += 1024) pairs[i] = srcp[i];
    for (int i = t; i < Pp; i += 1024) cntl[i] = 0;
    __syncthreads();
    for (int i = t; i < tot; i += 1024) atomicAdd(&cntl[pairs[i] >> 17], 1);
    __syncthreads();
    if (t < 512) sc[t] = (t < Pp) ? cntl[t] : 0;
    __syncthreads();
    for (int off = 1; off < 512; off <<= 1) {
        int v = 0;
        if (t < 512 && t >= off) v = sc[t - off];
        __syncthreads();
        if (t < 512) sc[t] += v;
        __syncthreads();
    }
    if (t < Pp) {
        int c = cntl[t];
        int ex = sc[t] - c;
        curl[t] = ex;
        int n = g * Pp + t;
        row_start[n] = g * GSTRIDE + ex;
        cnt_g[n] = c;
        dis[n] = rsqrtf((float)c + 1.0f);
    }
    __syncthreads();
    // scale hw rows of this graph by dis (fold of g1 = dis (.) (x@W1))
    for (int i = t; i < Pp * 8; i += 1024) {
        int l = i >> 3;
        float dn = rsqrtf((float)cntl[l] + 1.0f);
        float4 v = hwv[(size_t)g * (Pp * 8) + i];
        v.x *= dn; v.y *= dn; v.z *= dn; v.w *= dn;
        hwv[(size_t)g * (Pp * 8) + i] = v;
    }
    int* col = (int*)bucket;              // safe: stash done, block-local region
    for (int i = t; i < tot; i += 1024) {
        unsigned pr = pairs[i];
        int d = pr >> 17;
        int pos = atomicAdd(&curl[d], 1);
        col[g * GSTRIDE + pos] = (int)(pr & 0x1FFFFu);
    }
}

// ---------------- fused agg + next-layer GEMM ----------------
// wave-per-node gather (lane = e_sub*8+q, 8 edges x float4 in flight), butterfly
// reduce leaves the FULL row on every lane (channels 4q..4q+3). Epilogue:
// x_i = tanh(dis*acc+b); lane(e,q) computes the 4x4 partial of (x @ Wnext) for
// out-channels 4e..4e+3, k-block 4q..4q+3; shfl_xor over q completes the dot.
// W fragment lives in REGISTERS loaded from global at entry (W is 4KB, L1-hot;
// LDS staging caused 8-way bank conflicts: 512q byte stride == 0 mod 128).
template<int NEXT>
__global__ void k_aggF(const float4* __restrict__ gv, const int* __restrict__ row_start,
                       const int* __restrict__ cnt, const int* __restrict__ col,
                       const float* __restrict__ dis, const float4* __restrict__ bv,
                       float4* __restrict__ outv, const float* __restrict__ Wn,
                       float4* __restrict__ gnextv, float* __restrict__ g4) {
    int tid = threadIdx.x;
    int wave = tid >> 6;
    int lane = tid & 63;
    int e_sub = lane >> 3;
    int q = lane & 7;
    float4 w0, w1, w2, w3;
    if (NEXT == 32) {
        const float4* Wv = (const float4*)Wn;      // [32 k][8 float4]
        w0 = Wv[(4 * q + 0) * 8 + e_sub];
        w1 = Wv[(4 * q + 1) * 8 + e_sub];
        w2 = Wv[(4 * q + 2) * 8 + e_sub];
        w3 = Wv[(4 * q + 3) * 8 + e_sub];
    } else {
        w0 = ((const float4*)Wn)[q];
    }
    int n = blockIdx.x * 4 + wave;
    int st = row_start[n], cn = cnt[n];

    int colv = (lane < cn) ? col[st + lane] : 0;
    int iters = cn < 64 ? cn : 64;

    float4 a0 = make_float4(0.f, 0.f, 0.f, 0.f);
    float4 a1 = make_float4(0.f, 0.f, 0.f, 0.f);
    int base = 0;
    for (; base + 16 <= iters; base += 16) {       // uniform trip count
        int s0 = __shfl(colv, base + e_sub);
        int s1 = __shfl(colv, base + 8 + e_sub);
        float4 v0 = gv[s0 * 8 + q];
        float4 v1 = gv[s1 * 8 + q];
        a0.x += v0.x; a0.y += v0.y; a0.z += v0.z; a0.w += v0.w;
        a1.x += v1.x; a1.y += v1.y; a1.z += v1.z; a1.w += v1.w;
    }
    if (base < iters) {                             // uniform branch; shfls wave-wide
        int i0 = base + e_sub;
        int i1 = base + 8 + e_sub;
        int s0 = __shfl(colv, i0);
        int s1 = __shfl(colv, i1);
        if (i0 < iters) {
            float4 v = gv[s0 * 8 + q];
            a0.x += v.x; a0.y += v.y; a0.z += v.z; a0.w += v.w;
        }
        if (i1 < iters) {
            float4 v = gv[s1 * 8 + q];
            a1.x += v.x; a1.y += v.y; a1.z += v.z; a1.w += v.w;
        }
    }
    for (int j = 64 + e_sub; j < cn; j += 8) {      // rare high-degree tail
        int s = col[st + j];
        float4 v = gv[s * 8 + q];
        a0.x += v.x; a0.y += v.y; a0.z += v.z; a0.w += v.w;
    }
    a0.x += a1.x; a0.y += a1.y; a0.z += a1.z; a0.w += a1.w;
#pragma unroll
    for (int m = 8; m <= 32; m <<= 1) {             // all lanes end with full sums
        a0.x += __shfl_xor(a0.x, m);
        a0.y += __shfl_xor(a0.y, m);
        a0.z += __shfl_xor(a0.z, m);
        a0.w += __shfl_xor(a0.w, m);
    }
    float dn = dis[n];
    float4 self = gv[n * 8 + q];
    float4 bb = bv[q];
    float4 r;
    r.x = tanhf(dn * (a0.x + self.x) + bb.x);
    r.y = tanhf(dn * (a0.y + self.y) + bb.y);
    r.z = tanhf(dn * (a0.z + self.z) + bb.z);
    r.w = tanhf(dn * (a0.w + self.w) + bb.w);
    if (e_sub == 0) outv[n * 8 + q] = r;
    if (NEXT == 32) {
        float4 p;
        p.x = r.x * w0.x + r.y * w1.x + r.z * w2.x + r.w * w3.x;
        p.y = r.x * w0.y + r.y * w1.y + r.z * w2.y + r.w * w3.y;
        p.z = r.x * w0.z + r.y * w1.z + r.z * w2.z + r.w * w3.z;
        p.w = r.x * w0.w + r.y * w1.w + r.z * w2.w + r.w * w3.w;
#pragma unroll
        for (int m = 1; m <= 4; m <<= 1) {          // reduce over q (lane bits 0..2)
            p.x += __shfl_xor(p.x, m);
            p.y += __shfl_xor(p.y, m);
            p.z += __shfl_xor(p.z, m);
            p.w += __shfl_xor(p.w, m);
        }
        if (q == 0) {
            p.x *= dn; p.y *= dn; p.z *= dn; p.w *= dn;
            gnextv[n * 8 + e_sub] = p;
        }
    } else {
        float partial = r.x * w0.x + r.y * w0.y + r.z * w0.z + r.w * w0.w;
        partial += __shfl_xor(partial, 1);
        partial += __shfl_xor(partial, 2);
        partial += __shfl_xor(partial, 4);
        if (lane == 0) g4[n] = dn * partial;
    }
}

__global__ void k_agg1(const float* __restrict__ g4, const int* __restrict__ row_start,
                       const int* __restrict__ cnt, const int* __restrict__ col,
                       const float* __restrict__ dis, const float* __restrict__ b4,
                       float* __restrict__ x4) {
    int tid = threadIdx.x;
    int grp = tid >> 6, l = tid & 63;
    int n = blockIdx.x * 4 + grp;
    int st = row_start[n], cn = cnt[n];
    float acc = 0.f;
    for (int e = l; e < cn; e += 64) acc += g4[col[st + e]];
#pragma unroll
    for (int m = 32; m >= 1; m >>= 1) acc += __shfl_xor(acc, m);
    if (l == 0) x4[n] = tanhf(dis[n] * (acc + g4[n]) + b4[0]);
}

// ---------------- fused sort-pool + CNN + MLP head (one block per graph) -------------
__global__ void k_sorthead(const float* __restrict__ x1, const float* __restrict__ x2,
                           const float* __restrict__ x3, const float* __restrict__ x4,
                           const float* __restrict__ cw5, const float* __restrict__ cb5,
                           const float* __restrict__ cw6, const float* __restrict__ cb6,
                           const float* __restrict__ fw1, const float* __restrict__ fb1,
                           const float* __restrict__ fw2, const float* __restrict__ fb2,
                           float* __restrict__ out) {
    __shared__ float vals[Pp];
    __shared__ int sel[Kk];
    __shared__ float seq[Kk * Cc];
    __shared__ float w5l[16 * 97];
    __shared__ float t5[16 * 30];
    __shared__ float pl[16 * 15];
    __shared__ float w6l[32 * 16 * 5];
    __shared__ float c6f[352];
    __shared__ float h1[128];
    __shared__ float red[128];
    int gid = blockIdx.x, tid = threadIdx.x;
    for (int i = tid; i < Pp; i += 256) vals[i] = x4[gid * Pp + i];
    for (int i = tid; i < 16 * 97; i += 256) w5l[i] = cw5[i];
    for (int i = tid; i < 2560; i += 256) w6l[i] = cw6[i];
    __syncthreads();
    for (int i = tid; i < Pp; i += 256) {
        float v = vals[i];
        int rank = 0;
        for (int j = 0; j < Pp; j++) {
            float u = vals[j];
            rank += (u > v) || (u == v && j < i);   // stable desc rank
        }
        if (rank < Kk) sel[rank] = i;
    }
    __syncthreads();
    for (int t = tid; t < Kk * Cc; t += 256) {
        int k = t / Cc, c = t - k * Cc;
        int n = gid * Pp + sel[k];
        float v;
        if (c < 32)      v = x1[n * 32 + c];
        else if (c < 64) v = x2[n * 32 + c - 32];
        else if (c < 96) v = x3[n * 32 + c - 64];
        else             v = vals[sel[k]];
        seq[t] = v;
    }
    __syncthreads();
    for (int idx = tid; idx < 480; idx += 256) {
        int ch = idx / 30, t = idx - ch * 30;
        float acc = cb5[ch];
        for (int i = 0; i < 97; i++) acc += w5l[ch * 97 + i] * seq[t * 97 + i];
        t5[ch * 30 + t] = fmaxf(acc, 0.f);
    }
    __syncthreads();
    for (int idx = tid; idx < 240; idx += 256) {
        int ch = idx / 15, t = idx - ch * 15;
        pl[idx] = fmaxf(t5[ch * 30 + 2 * t], t5[ch * 30 + 2 * t + 1]);
    }
    __syncthreads();
    for (int idx = tid; idx < 352; idx += 256) {
        int o = idx / 11, t = idx - o * 11;
        float acc = cb6[o];
        for (int i = 0; i < 16; i++)
            for (int j = 0; j < 5; j++)
                acc += w6l[o * 80 + i * 5 + j] * pl[i * 15 + t + j];
        c6f[o * 11 + t] = fmaxf(acc, 0.f);
    }
    __syncthreads();
    if (tid < 128) {
        float acc = fb1[tid];
        for (int i = 0; i < 352; i++) acc += c6f[i] * fw1[i * 128 + tid];
        h1[tid] = fmaxf(acc, 0.f);
    }
    __syncthreads();
    if (tid < 128) red[tid] = h1[tid] * fw2[tid];
    __syncthreads();
    for (int off = 64; off >= 1; off >>= 1) {
        if (tid < off) red[tid] += red[tid + off];
        __syncthreads();
    }
    if (tid == 0) out[gid] = red[0] + fb2[0];
}

extern "C" void kernel_launch(void* const* d_in, const int* in_sizes, int n_in,
                              void* d_out, int out_size, void* d_ws, size_t ws_size,
                              hipStream_t stream) {
    const float* x   = (const float*)d_in[0];
    const int*   ei  = (const int*)d_in[1];
    const float* W1  = (const float*)d_in[3];
    const float* b1  = (const float*)d_in[4];
    const float* W2  = (const float*)d_in[5];
    const float* b2  = (const float*)d_in[6];
    const float* W3  = (const float*)d_in[7];
    const float* b3  = (const float*)d_in[8];
    const float* W4  = (const float*)d_in[9];
    const float* b4  = (const float*)d_in[10];
    const float* cw5 = (const float*)d_in[11];
    const float* cb5 = (const float*)d_in[12];
    const float* cw6 = (const float*)d_in[13];
    const float* cb6 = (const float*)d_in[14];
    const float* fw1 = (const float*)d_in[15];
    const float* fb1 = (const float*)d_in[16];
    const float* fw2 = (const float*)d_in[17];
    const float* fb2 = (const float*)d_in[18];
    float* out = (float*)d_out;

    char* p = (char*)d_ws;
    auto alloc = [&](size_t bytes) {
        char* r = p;
        p += (bytes + 255) & ~size_t(255);
        return r;
    };
    float*    dis       = (float*)alloc((size_t)Nn * 4);
    int*      cnt       = (int*)  alloc((size_t)Nn * 4);
    int*      row_start = (int*)  alloc((size_t)Nn * 4);
    int*      gcnt      = (int*)  alloc((size_t)Gg * 4);
    unsigned* bucket    = (unsigned*)alloc((size_t)Gg * GSTRIDE * 4); // reused as col
    float*    x1        = (float*)alloc((size_t)Nn * 32 * 4);
    float*    x2        = (float*)alloc((size_t)Nn * 32 * 4);
    float*    x3        = (float*)alloc((size_t)Nn * 32 * 4);
    float*    x4        = (float*)alloc((size_t)Nn * 4);
    float*    g_a       = (float*)alloc((size_t)Nn * 32 * 4);
    float*    g_b       = (float*)alloc((size_t)Nn * 32 * 4);
    int*      col       = (int*)bucket;
    float*    g4        = g_b;              // g_b free by the time aggF<1> runs

    hipMemsetAsync(gcnt, 0, (size_t)Gg * 4, stream);
    k_bs_gemm<<<NBS + Nn / 32, 1024, 0, stream>>>(ei, gcnt, bucket, x, W1, g_a);
    k_build<<<Gg, 1024, 0, stream>>>(gcnt, bucket, row_start, cnt, dis, (float4*)g_a);

    // layer 1: agg(g_a) -> x1, g2 -> g_b
    k_aggF<32><<<Nn / 4, 256, 0, stream>>>((const float4*)g_a, row_start, cnt, col, dis,
                                           (const float4*)b1, (float4*)x1, W2,
                                           (float4*)g_b, nullptr);
    // layer 2: agg(g_b) -> x2, g3 -> g_a
    k_aggF<32><<<Nn / 4, 256, 0, stream>>>((const float4*)g_b, row_start, cnt, col, dis,
                                           (const float4*)b2, (float4*)x2, W3,
                                           (float4*)g_a, nullptr);
    // layer 3: agg(g_a) -> x3, g4 (1ch)
    k_aggF<1><<<Nn / 4, 256, 0, stream>>>((const float4*)g_a, row_start, cnt, col, dis,
                                          (const float4*)b3, (float4*)x3, W4,
                                          nullptr, g4);
    // layer 4 aggregation (scalar channel)
    k_agg1<<<Nn / 4, 256, 0, stream>>>(g4, row_start, cnt, col, dis, b4, x4);

    k_sorthead<<<Gg, 256, 0, stream>>>(x1, x2, x3, x4, cw5, cb5, cw6, cb6,
                                       fw1, fb1, fw2, fb2, out);
}

// Round 10
// 422.083 us; speedup vs baseline: 1.1555x; 1.1555x over previous
//
#include <hip/hip_runtime.h>
#include <math.h>

#define Nn 102400
#define Gg 256
#define Pp 400
#define Ee 3276800
#define Ff 128
#define Kk 30
#define Cc 97

#define GSTRIDE 16384     // col slots per graph (avg fill 12800, sd ~113)
#define CHUNK 8192        // edges per binsort block
#define NBS 400           // binsort blocks

// ---------------- K1: binsort (blocks 0..399)  ||  gemm 128->32 (blocks 400..3599) ----
struct BSmem {
    unsigned reord[CHUNK];        // 32 KB
    unsigned char sg[CHUNK];      // 8 KB
    int cntl[Gg];
    int ginc[Gg];
    int gex[Gg];
    int gbase[Gg];
    int cur[Gg];
};
struct GMmem {
    float Wl[128 * 32];           // 16 KB
    float hrow[32][128];          // 16 KB
};
union KUmem { BSmem bs; GMmem gm; };

__global__ void __launch_bounds__(1024) k_bs_gemm(const int* __restrict__ ei,
                                                  int* __restrict__ gcnt,
                                                  unsigned* __restrict__ bucket,
                                                  const float* __restrict__ x,
                                                  const float* __restrict__ W1,
                                                  float* __restrict__ hw) {
    __shared__ __align__(16) KUmem u;
    int t = threadIdx.x;
    if (blockIdx.x < NBS) {
        // ---- binsort role ----
        int base = blockIdx.x * CHUNK;
        for (int i = t; i < Gg; i += 1024) u.bs.cntl[i] = 0;
        __syncthreads();
        unsigned val[8];
        int vg[8];
        bool ok[8];
#pragma unroll
        for (int j = 0; j < 8; j++) {
            int e = base + j * 1024 + t;
            int s = ei[e], d = ei[Ee + e];
            ok[j] = (s != d);
            int gph = d / Pp;
            vg[j] = gph;
            val[j] = (unsigned)s | ((unsigned)(d - gph * Pp) << 17);
            if (ok[j]) atomicAdd(&u.bs.cntl[gph], 1);
        }
        __syncthreads();
        if (t < Gg) u.bs.ginc[t] = u.bs.cntl[t];
        __syncthreads();
        for (int off = 1; off < Gg; off <<= 1) {
            int v = 0;
            if (t < Gg && t >= off) v = u.bs.ginc[t - off];
            __syncthreads();
            if (t < Gg) u.bs.ginc[t] += v;
            __syncthreads();
        }
        if (t < Gg) {
            int ex = u.bs.ginc[t] - u.bs.cntl[t];
            u.bs.gex[t] = ex;
            u.bs.cur[t] = ex;
            u.bs.gbase[t] = atomicAdd(&gcnt[t], u.bs.cntl[t]);
        }
        __syncthreads();
#pragma unroll
        for (int j = 0; j < 8; j++)
            if (ok[j]) {
                int pos = atomicAdd(&u.bs.cur[vg[j]], 1);
                u.bs.reord[pos] = val[j];
                u.bs.sg[pos] = (unsigned char)vg[j];
            }
        __syncthreads();
        int tot = u.bs.ginc[Gg - 1];
        for (int i = t; i < tot; i += 1024) {
            int g = u.bs.sg[i];
            bucket[g * GSTRIDE + u.bs.gbase[g] + (i - u.bs.gex[g])] = u.bs.reord[i];
        }
    } else {
        // ---- gemm role: 32 rows/block ----
        ((float4*)u.gm.Wl)[t] = ((const float4*)W1)[t];
        int grp = t >> 5, c = t & 31;
        int n = (blockIdx.x - NBS) * 32 + grp;
        ((float4*)u.gm.hrow[grp])[c] = ((const float4*)(x + (size_t)n * 128))[c];
        __syncthreads();
        float acc = 0.f;
#pragma unroll 8
        for (int k = 0; k < 128; k++) acc += u.gm.hrow[grp][k] * u.gm.Wl[k * 32 + c];
        hw[(size_t)n * 32 + c] = acc;
    }
}

// ---------------- CSR build: per-graph counting sort + dis + scale hw by dis ---------
__global__ void __launch_bounds__(1024) k_build(const int* __restrict__ gcnt,
                                                unsigned* __restrict__ bucket, /* also col out */
                                                int* __restrict__ row_start,
                                                int* __restrict__ cnt_g,
                                                float* __restrict__ dis,
                                                float4* __restrict__ hwv) {
    __shared__ unsigned pairs[GSTRIDE];   // 64 KB stash
    __shared__ int cntl[Pp];
    __shared__ int curl[Pp];
    __shared__ int sc[512];
    int g = blockIdx.x, t = threadIdx.x;
    int tot = gcnt[g];
    if (tot > GSTRIDE) tot = GSTRIDE;
    const unsigned* srcp = bucket + (size_t)g * GSTRIDE;
    for (int i = t; i < tot; i += 1024) pairs[i] = srcp[i];
    for (int i = t; i < Pp; i += 1024) cntl[i] = 0;
    __syncthreads();
    for (int i = t; i < tot; i += 1024) atomicAdd(&cntl[pairs[i] >> 17], 1);
    __syncthreads();
    if (t < 512) sc[t] = (t < Pp) ? cntl[t] : 0;
    __syncthreads();
    for (int off = 1; off < 512; off <<= 1) {
        int v = 0;
        if (t < 512 && t >= off) v = sc[t - off];
        __syncthreads();
        if (t < 512) sc[t] += v;
        __syncthreads();
    }
    if (t < Pp) {
        int c = cntl[t];
        int ex = sc[t] - c;
        curl[t] = ex;
        int n = g * Pp + t;
        row_start[n] = g * GSTRIDE + ex;
        cnt_g[n] = c;
        dis[n] = rsqrtf((float)c + 1.0f);
    }
    __syncthreads();
    // scale hw rows of this graph by dis (fold of g1 = dis (.) (x@W1))
    for (int i = t; i < Pp * 8; i += 1024) {
        int l = i >> 3;
        float dn = rsqrtf((float)cntl[l] + 1.0f);
        float4 v = hwv[(size_t)g * (Pp * 8) + i];
        v.x *= dn; v.y *= dn; v.z *= dn; v.w *= dn;
        hwv[(size_t)g * (Pp * 8) + i] = v;
    }
    int* col = (int*)bucket;              // safe: stash done, block-local region
    for (int i = t; i < tot; i += 1024) {
        unsigned pr = pairs[i];
        int d = pr >> 17;
        int pos = atomicAdd(&curl[d], 1);
        col[g * GSTRIDE + pos] = (int)(pr & 0x1FFFFu);
    }
}

// ---------------- fused agg + next-layer GEMM ----------------
// wave-per-node gather (lane = e_sub*8+q, 8 edges x float4 in flight), butterfly
// reduce leaves the FULL row on every lane (channels 4q..4q+3). Epilogue:
// x_i = tanh(dis*acc+b); lane(e,q) computes the 4x4 partial of (x @ Wnext) for
// out-channels 4e..4e+3, k-block 4q..4q+3; shfl_xor over q completes the dot.
// W staged in LDS pre-transposed to Wf[j][lane] so the epilogue ds_read_b128 is
// lane-contiguous (16B stride) = conflict-free. (Round 8's [k][8] layout was
// 8-way conflicted: q-stride 512B == 0 mod 128. Round 9's register-W sank the
// global loads into the tail -> latency exposed.)
template<int NEXT>
__global__ void k_aggF(const float4* __restrict__ gv, const int* __restrict__ row_start,
                       const int* __restrict__ cnt, const int* __restrict__ col,
                       const float* __restrict__ dis, const float4* __restrict__ bv,
                       float4* __restrict__ outv, const float* __restrict__ Wn,
                       float4* __restrict__ gnextv, float* __restrict__ g4) {
    __shared__ __align__(16) float4 Wf[4][64];
    int tid = threadIdx.x;
    if (NEXT == 32) {
        // stage transposed: Wf[j][l] = W rows (4q+j), cols 4e..4e+3, l=(e<<3)|q
        int j = tid >> 6, l = tid & 63;
        int qq = l & 7, ee = l >> 3;
        Wf[j][l] = ((const float4*)Wn)[(4 * qq + j) * 8 + ee];
        __syncthreads();
    }
    int wave = tid >> 6;
    int lane = tid & 63;
    int e_sub = lane >> 3;
    int q = lane & 7;
    int n = blockIdx.x * 4 + wave;
    int st = row_start[n], cn = cnt[n];

    int colv = (lane < cn) ? col[st + lane] : 0;
    int iters = cn < 64 ? cn : 64;

    float4 a0 = make_float4(0.f, 0.f, 0.f, 0.f);
    float4 a1 = make_float4(0.f, 0.f, 0.f, 0.f);
    int base = 0;
    for (; base + 16 <= iters; base += 16) {       // uniform trip count
        int s0 = __shfl(colv, base + e_sub);
        int s1 = __shfl(colv, base + 8 + e_sub);
        float4 v0 = gv[s0 * 8 + q];
        float4 v1 = gv[s1 * 8 + q];
        a0.x += v0.x; a0.y += v0.y; a0.z += v0.z; a0.w += v0.w;
        a1.x += v1.x; a1.y += v1.y; a1.z += v1.z; a1.w += v1.w;
    }
    if (base < iters) {                             // uniform branch; shfls wave-wide
        int i0 = base + e_sub;
        int i1 = base + 8 + e_sub;
        int s0 = __shfl(colv, i0);
        int s1 = __shfl(colv, i1);
        if (i0 < iters) {
            float4 v = gv[s0 * 8 + q];
            a0.x += v.x; a0.y += v.y; a0.z += v.z; a0.w += v.w;
        }
        if (i1 < iters) {
            float4 v = gv[s1 * 8 + q];
            a1.x += v.x; a1.y += v.y; a1.z += v.z; a1.w += v.w;
        }
    }
    for (int j = 64 + e_sub; j < cn; j += 8) {      // rare high-degree tail
        int s = col[st + j];
        float4 v = gv[s * 8 + q];
        a0.x += v.x; a0.y += v.y; a0.z += v.z; a0.w += v.w;
    }
    a0.x += a1.x; a0.y += a1.y; a0.z += a1.z; a0.w += a1.w;
#pragma unroll
    for (int m = 8; m <= 32; m <<= 1) {             // all lanes end with full sums
        a0.x += __shfl_xor(a0.x, m);
        a0.y += __shfl_xor(a0.y, m);
        a0.z += __shfl_xor(a0.z, m);
        a0.w += __shfl_xor(a0.w, m);
    }
    float dn = dis[n];
    float4 self = gv[n * 8 + q];
    float4 bb = bv[q];
    float4 r;
    r.x = tanhf(dn * (a0.x + self.x) + bb.x);
    r.y = tanhf(dn * (a0.y + self.y) + bb.y);
    r.z = tanhf(dn * (a0.z + self.z) + bb.z);
    r.w = tanhf(dn * (a0.w + self.w) + bb.w);
    if (e_sub == 0) outv[n * 8 + q] = r;
    if (NEXT == 32) {
        float4 w0 = Wf[0][lane];
        float4 w1 = Wf[1][lane];
        float4 w2 = Wf[2][lane];
        float4 w3 = Wf[3][lane];
        float4 p;
        p.x = r.x * w0.x + r.y * w1.x + r.z * w2.x + r.w * w3.x;
        p.y = r.x * w0.y + r.y * w1.y + r.z * w2.y + r.w * w3.y;
        p.z = r.x * w0.z + r.y * w1.z + r.z * w2.z + r.w * w3.z;
        p.w = r.x * w0.w + r.y * w1.w + r.z * w2.w + r.w * w3.w;
#pragma unroll
        for (int m = 1; m <= 4; m <<= 1) {          // reduce over q (lane bits 0..2)
            p.x += __shfl_xor(p.x, m);
            p.y += __shfl_xor(p.y, m);
            p.z += __shfl_xor(p.z, m);
            p.w += __shfl_xor(p.w, m);
        }
        if (q == 0) {
            p.x *= dn; p.y *= dn; p.z *= dn; p.w *= dn;
            gnextv[n * 8 + e_sub] = p;
        }
    } else {
        float4 w = ((const float4*)Wn)[q];
        float partial = r.x * w.x + r.y * w.y + r.z * w.z + r.w * w.w;
        partial += __shfl_xor(partial, 1);
        partial += __shfl_xor(partial, 2);
        partial += __shfl_xor(partial, 4);
        if (lane == 0) g4[n] = dn * partial;
    }
}

// ---------------- fused layer-4 agg + sort-pool + CNN + MLP head (1 block/graph) -----
__global__ void __launch_bounds__(1024) k_tail(
        const float* __restrict__ g4, const int* __restrict__ row_start,
        const int* __restrict__ cnt, const int* __restrict__ col,
        const float* __restrict__ dis, const float* __restrict__ b4,
        const float* __restrict__ x1, const float* __restrict__ x2,
        const float* __restrict__ x3,
        const float* __restrict__ cw5, const float* __restrict__ cb5,
        const float* __restrict__ cw6, const float* __restrict__ cb6,
        const float* __restrict__ fw1, const float* __restrict__ fb1,
        const float* __restrict__ fw2, const float* __restrict__ fb2,
        float* __restrict__ out) {
    __shared__ float vals[Pp];
    __shared__ int sel[Kk];
    __shared__ float seq[Kk * Cc];
    __shared__ float w5l[16 * 97];
    __shared__ float t5[16 * 30];
    __shared__ float pl[16 * 15];
    __shared__ float w6l[32 * 16 * 5];
    __shared__ float c6f[352];
    __shared__ float h1[128];
    __shared__ float red[128];
    int gid = blockIdx.x, tid = threadIdx.x;
    // ---- layer-4 aggregation: one 32-lane half-wave per node ----
    int half = tid >> 5;          // 0..31
    int hl = tid & 31;
    float bb4 = b4[0];
    for (int nd = half; nd < Pp; nd += 32) {
        int n = gid * Pp + nd;
        int st = row_start[n], cn = cnt[n];
        float acc = 0.f;
        for (int e = hl; e < cn; e += 32) acc += g4[col[st + e]];
#pragma unroll
        for (int m = 16; m >= 1; m >>= 1) acc += __shfl_xor(acc, m);
        if (hl == 0) vals[nd] = tanhf(dis[n] * (acc + g4[n]) + bb4);
    }
    for (int i = tid; i < 16 * 97; i += 1024) w5l[i] = cw5[i];
    for (int i = tid; i < 2560; i += 1024) w6l[i] = cw6[i];
    __syncthreads();
    // ---- sort-pool: stable desc rank by vals ----
    if (tid < Pp) {
        float v = vals[tid];
        int rank = 0;
        for (int j = 0; j < Pp; j++) {
            float u = vals[j];
            rank += (u > v) || (u == v && j < tid);
        }
        if (rank < Kk) sel[rank] = tid;
    }
    __syncthreads();
    for (int t = tid; t < Kk * Cc; t += 1024) {
        int k = t / Cc, c = t - k * Cc;
        int n = gid * Pp + sel[k];
        float v;
        if (c < 32)      v = x1[n * 32 + c];
        else if (c < 64) v = x2[n * 32 + c - 32];
        else if (c < 96) v = x3[n * 32 + c - 64];
        else             v = vals[sel[k]];
        seq[t] = v;
    }
    __syncthreads();
    // ---- conv5 (k=97, stride 97) + relu ----
    for (int idx = tid; idx < 480; idx += 1024) {
        int ch = idx / 30, t = idx - ch * 30;
        float acc = cb5[ch];
        for (int i = 0; i < 97; i++) acc += w5l[ch * 97 + i] * seq[t * 97 + i];
        t5[ch * 30 + t] = fmaxf(acc, 0.f);
    }
    __syncthreads();
    for (int idx = tid; idx < 240; idx += 1024) {
        int ch = idx / 15, t = idx - ch * 15;
        pl[idx] = fmaxf(t5[ch * 30 + 2 * t], t5[ch * 30 + 2 * t + 1]);
    }
    __syncthreads();
    for (int idx = tid; idx < 352; idx += 1024) {
        int o = idx / 11, t = idx - o * 11;
        float acc = cb6[o];
        for (int i = 0; i < 16; i++)
            for (int j = 0; j < 5; j++)
                acc += w6l[o * 80 + i * 5 + j] * pl[i * 15 + t + j];
        c6f[o * 11 + t] = fmaxf(acc, 0.f);
    }
    __syncthreads();
    if (tid < 128) {
        float acc = fb1[tid];
        for (int i = 0; i < 352; i++) acc += c6f[i] * fw1[i * 128 + tid];
        h1[tid] = fmaxf(acc, 0.f);
    }
    __syncthreads();
    if (tid < 128) red[tid] = h1[tid] * fw2[tid];
    __syncthreads();
    for (int off = 64; off >= 1; off >>= 1) {
        if (tid < off) red[tid] += red[tid + off];
        __syncthreads();
    }
    if (tid == 0) out[gid] = red[0] + fb2[0];
}

extern "C" void kernel_launch(void* const* d_in, const int* in_sizes, int n_in,
                              void* d_out, int out_size, void* d_ws, size_t ws_size,
                              hipStream_t stream) {
    const float* x   = (const float*)d_in[0];
    const int*   ei  = (const int*)d_in[1];
    const float* W1  = (const float*)d_in[3];
    const float* b1  = (const float*)d_in[4];
    const float* W2  = (const float*)d_in[5];
    const float* b2  = (const float*)d_in[6];
    const float* W3  = (const float*)d_in[7];
    const float* b3  = (const float*)d_in[8];
    const float* W4  = (const float*)d_in[9];
    const float* b4  = (const float*)d_in[10];
    const float* cw5 = (const float*)d_in[11];
    const float* cb5 = (const float*)d_in[12];
    const float* cw6 = (const float*)d_in[13];
    const float* cb6 = (const float*)d_in[14];
    const float* fw1 = (const float*)d_in[15];
    const float* fb1 = (const float*)d_in[16];
    const float* fw2 = (const float*)d_in[17];
    const float* fb2 = (const float*)d_in[18];
    float* out = (float*)d_out;

    char* p = (char*)d_ws;
    auto alloc = [&](size_t bytes) {
        char* r = p;
        p += (bytes + 255) & ~size_t(255);
        return r;
    };
    float*    dis       = (float*)alloc((size_t)Nn * 4);
    int*      cnt       = (int*)  alloc((size_t)Nn * 4);
    int*      row_start = (int*)  alloc((size_t)Nn * 4);
    int*      gcnt      = (int*)  alloc((size_t)Gg * 4);
    unsigned* bucket    = (unsigned*)alloc((size_t)Gg * GSTRIDE * 4); // reused as col
    float*    x1        = (float*)alloc((size_t)Nn * 32 * 4);
    float*    x2        = (float*)alloc((size_t)Nn * 32 * 4);
    float*    x3        = (float*)alloc((size_t)Nn * 32 * 4);
    float*    g_a       = (float*)alloc((size_t)Nn * 32 * 4);
    float*    g_b       = (float*)alloc((size_t)Nn * 32 * 4);
    int*      col       = (int*)bucket;
    float*    g4        = g_b;              // g_b free by the time aggF<1> runs

    hipMemsetAsync(gcnt, 0, (size_t)Gg * 4, stream);
    k_bs_gemm<<<NBS + Nn / 32, 1024, 0, stream>>>(ei, gcnt, bucket, x, W1, g_a);
    k_build<<<Gg, 1024, 0, stream>>>(gcnt, bucket, row_start, cnt, dis, (float4*)g_a);

    // layer 1: agg(g_a) -> x1, g2 -> g_b
    k_aggF<32><<<Nn / 4, 256, 0, stream>>>((const float4*)g_a, row_start, cnt, col, dis,
                                           (const float4*)b1, (float4*)x1, W2,
                                           (float4*)g_b, nullptr);
    // layer 2: agg(g_b) -> x2, g3 -> g_a
    k_aggF<32><<<Nn / 4, 256, 0, stream>>>((const float4*)g_b, row_start, cnt, col, dis,
                                           (const float4*)b2, (float4*)x2, W3,
                                           (float4*)g_a, nullptr);
    // layer 3: agg(g_a) -> x3, g4 (1ch)
    k_aggF<1><<<Nn / 4, 256, 0, stream>>>((const float4*)g_a, row_start, cnt, col, dis,
                                          (const float4*)b3, (float4*)x3, W4,
                                          nullptr, g4);
    // layer 4 agg + sort-pool + CNN + MLP, fused per graph
    k_tail<<<Gg, 1024, 0, stream>>>(g4, row_start, cnt, col, dis, b4,
                                    x1, x2, x3, cw5, cb5, cw6, cb6,
                                    fw1, fb1, fw2, fb2, out);
}